// Round 4
// baseline (1275.471 us; speedup 1.0000x reference)
//
#include <hip/hip_runtime.h>

#define N_NODES 100000
#define F 64
#define C 32
#define KH 3
#define E 1600000
#define NE_TOT (KH * E)                 // 4,800,000

#define BKT_SHIFT 7                     // 128 rows per bucket
#define ROWS_PER_BKT 128
#define NB ((N_NODES + ROWS_PER_BKT - 1) / ROWS_PER_BKT)   // 782
#define CHUNK 8192
#define NBIN_BLK ((NE_TOT + CHUNK - 1) / CHUNK)            // 586
#define COL_MASK 0xFFFFF                // 20 bits for col (col < 100000 < 2^17)

// ---------------------------------------------------------------------------
// K1: y[n, c] = sum_f x[n, f] * W[f, c]   (all fp32)
// ---------------------------------------------------------------------------
__global__ __launch_bounds__(256) void gemm_xw(const float* __restrict__ x,
                                               const float* __restrict__ W,
                                               float* __restrict__ y) {
    __shared__ float Ws[F * C];  // 8 KB
    for (int i = threadIdx.x; i < F * C; i += 256) Ws[i] = W[i];
    __syncthreads();

    const int node = blockIdx.x * 256 + threadIdx.x;
    if (node >= N_NODES) return;

    const float4* xp = (const float4*)(x + (size_t)node * F);
    float acc[C];
#pragma unroll
    for (int c = 0; c < C; c++) acc[c] = 0.f;

#pragma unroll
    for (int i = 0; i < 16; i++) {
        float4 v = xp[i];
        const int f = i * 4;
#pragma unroll
        for (int c = 0; c < C; c++) {
            acc[c] += v.x * Ws[(f + 0) * C + c];
            acc[c] += v.y * Ws[(f + 1) * C + c];
            acc[c] += v.z * Ws[(f + 2) * C + c];
            acc[c] += v.w * Ws[(f + 3) * C + c];
        }
    }

    float4* yo = (float4*)(y + (size_t)node * C);
#pragma unroll
    for (int i = 0; i < 8; i++)
        yo[i] = make_float4(acc[4 * i], acc[4 * i + 1], acc[4 * i + 2], acc[4 * i + 3]);
}

// ---------------------------------------------------------------------------
// K2: bucket histogram (LDS-aggregated)
// ---------------------------------------------------------------------------
__global__ __launch_bounds__(256) void hist_bkt(const int* __restrict__ rows,
                                                int* __restrict__ bktcnt) {
    __shared__ int h[NB];
    for (int i = threadIdx.x; i < NB; i += 256) h[i] = 0;
    __syncthreads();

    const int base = blockIdx.x * CHUNK;
#pragma unroll 4
    for (int j = 0; j < CHUNK / 256; j++) {
        const int e = base + j * 256 + threadIdx.x;
        if (e < NE_TOT) atomicAdd(&h[rows[e] >> BKT_SHIFT], 1);
    }
    __syncthreads();
    for (int i = threadIdx.x; i < NB; i += 256)
        if (h[i]) atomicAdd(&bktcnt[i], h[i]);
}

// ---------------------------------------------------------------------------
// K3: exclusive scan of bucket counts (single block) -> bkt_start, cursor
// ---------------------------------------------------------------------------
__global__ __launch_bounds__(1024) void scan_bkt(const int* __restrict__ cnt,
                                                 int* __restrict__ bkt_start,
                                                 int* __restrict__ cursor) {
    __shared__ int s[1024];
    const int t = threadIdx.x;
    s[t] = (t < NB) ? cnt[t] : 0;
    __syncthreads();
    for (int off = 1; off < 1024; off <<= 1) {
        int v = s[t];
        int a = (t >= off) ? s[t - off] : 0;
        __syncthreads();
        s[t] = v + a;
        __syncthreads();
    }
    if (t < NB) {
        const int ex = (t == 0) ? 0 : s[t - 1];
        bkt_start[t] = ex;
        cursor[t] = ex;
    }
    if (t == NB) bkt_start[NB] = s[NB - 1];
}

// ---------------------------------------------------------------------------
// K4: bin edges into buckets; record = (rowLocal<<20 | col, w_bits)
// ---------------------------------------------------------------------------
__global__ __launch_bounds__(256) void bin_k(
    const float* __restrict__ vals, const int* __restrict__ rows,
    const int* __restrict__ cols, const float* __restrict__ alpha,
    int* __restrict__ g_cursor, int2* __restrict__ recs) {
    __shared__ int h[NB];
    __shared__ int cur[NB];
    for (int i = threadIdx.x; i < NB; i += 256) h[i] = 0;
    __syncthreads();

    const int base = blockIdx.x * CHUNK;
    // phase 1: count
#pragma unroll 4
    for (int j = 0; j < CHUNK / 256; j++) {
        const int e = base + j * 256 + threadIdx.x;
        if (e < NE_TOT) atomicAdd(&h[rows[e] >> BKT_SHIFT], 1);
    }
    __syncthreads();
    // phase 2: reserve global ranges
    for (int i = threadIdx.x; i < NB; i += 256)
        cur[i] = atomicAdd(&g_cursor[i], h[i]);
    __syncthreads();
    // phase 3: place records
#pragma unroll 4
    for (int j = 0; j < CHUNK / 256; j++) {
        const int e = base + j * 256 + threadIdx.x;
        if (e >= NE_TOT) continue;
        const int row = rows[e];
        const int b = row >> BKT_SHIFT;
        const int k = (e >= 2 * E) ? 2 : (e >= E) ? 1 : 0;
        const float w = vals[e] * alpha[k];
        const int slot = atomicAdd(&cur[b], 1);
        const int packed = cols[e] | ((row & (ROWS_PER_BKT - 1)) << 20);
        recs[slot] = make_int2(packed, __float_as_int(w));
    }
}

// ---------------------------------------------------------------------------
// K5: accumulate — one block per bucket, 128x32 fp32 tile in LDS
// 32-lane group per edge (one lane per channel), ds_add_f32, fused bias.
// ---------------------------------------------------------------------------
__global__ __launch_bounds__(512) void acc_k(
    const int* __restrict__ bkt_start, const int2* __restrict__ recs,
    const float* __restrict__ y, const float* __restrict__ bias,
    float* __restrict__ out) {
    __shared__ float accs[ROWS_PER_BKT * C];  // 16 KB
    const int tid = threadIdx.x;
    for (int i = tid; i < ROWS_PER_BKT * C; i += 512) accs[i] = 0.f;
    __syncthreads();

    const int b = blockIdx.x;
    const int start = bkt_start[b];
    const int end = bkt_start[b + 1];
    const int grp = tid >> 5;       // 16 groups
    const int c = tid & 31;

    int i = start + grp;
    const int step = 16;
    for (; i + 3 * step < end; i += 4 * step) {
        const int2 r0 = recs[i + 0 * step];
        const int2 r1 = recs[i + 1 * step];
        const int2 r2 = recs[i + 2 * step];
        const int2 r3 = recs[i + 3 * step];
        const float p0 = y[(size_t)(r0.x & COL_MASK) * C + c];
        const float p1 = y[(size_t)(r1.x & COL_MASK) * C + c];
        const float p2 = y[(size_t)(r2.x & COL_MASK) * C + c];
        const float p3 = y[(size_t)(r3.x & COL_MASK) * C + c];
        unsafeAtomicAdd(&accs[(r0.x >> 20) * C + c], __int_as_float(r0.y) * p0);
        unsafeAtomicAdd(&accs[(r1.x >> 20) * C + c], __int_as_float(r1.y) * p1);
        unsafeAtomicAdd(&accs[(r2.x >> 20) * C + c], __int_as_float(r2.y) * p2);
        unsafeAtomicAdd(&accs[(r3.x >> 20) * C + c], __int_as_float(r3.y) * p3);
    }
    for (; i < end; i += step) {
        const int2 r0 = recs[i];
        const float p0 = y[(size_t)(r0.x & COL_MASK) * C + c];
        unsafeAtomicAdd(&accs[(r0.x >> 20) * C + c], __int_as_float(r0.y) * p0);
    }
    __syncthreads();

    // epilogue: out = accs + bias (coalesced)
    const int row0 = b << BKT_SHIFT;
    const int nrows = min(ROWS_PER_BKT, N_NODES - row0);
    for (int idx = tid; idx < nrows * C; idx += 512)
        out[(size_t)row0 * C + idx] = accs[idx] + bias[idx & (C - 1)];
}

// ---------------------------------------------------------------------------
extern "C" void kernel_launch(void* const* d_in, const int* in_sizes, int n_in,
                              void* d_out, int out_size, void* d_ws, size_t ws_size,
                              hipStream_t stream) {
    const float* x         = (const float*)d_in[0];
    const float* edge_vals = (const float*)d_in[1];
    const float* W         = (const float*)d_in[2];
    const float* b         = (const float*)d_in[3];
    const float* alpha     = (const float*)d_in[4];
    const int*   edge_rows = (const int*)d_in[5];
    const int*   edge_cols = (const int*)d_in[6];
    float*       out       = (float*)d_out;          // [N, C] fp32

    // ws layout (4 B units)
    int* wsi = (int*)d_ws;
    float* y         = (float*)wsi;                  // 3,200,000 f32 (12.8 MB)
    int*   bktcnt    = wsi + 3200000;                // NB (pad 1024)
    int*   bkt_start = wsi + 3201024;                // NB+1 (pad 1024)
    int*   g_cursor  = wsi + 3202048;                // NB (pad 1024)
    int2*  recs      = (int2*)(wsi + 3203072);       // 4.8M int2 (38.4 MB), 8B-aligned

    hipMemsetAsync(bktcnt, 0, NB * sizeof(int), stream);

    gemm_xw<<<(N_NODES + 255) / 256, 256, 0, stream>>>(x, W, y);

    hist_bkt<<<NBIN_BLK, 256, 0, stream>>>(edge_rows, bktcnt);
    scan_bkt<<<1, 1024, 0, stream>>>(bktcnt, bkt_start, g_cursor);
    bin_k<<<NBIN_BLK, 256, 0, stream>>>(edge_vals, edge_rows, edge_cols, alpha,
                                        g_cursor, recs);
    acc_k<<<NB, 512, 0, stream>>>(bkt_start, recs, y, b, out);
}

// Round 5
// 1094.613 us; speedup vs baseline: 1.1652x; 1.1652x over previous
//
#include <hip/hip_runtime.h>

#define N_NODES 100000
#define F 64
#define C 32
#define KH 3
#define E 1600000
#define NE_TOT (KH * E)                 // 4,800,000

#define BKT_SHIFT 7                     // 128 rows per bucket
#define ROWS_PER_BKT 128
#define NB ((N_NODES + ROWS_PER_BKT - 1) / ROWS_PER_BKT)   // 782
#define CHUNK 8192
#define NBIN_BLK ((NE_TOT + CHUNK - 1) / CHUNK)            // 586
#define COL_MASK 0xFFFFF
#define SPLIT 4                         // edge sub-ranges per bucket

// ---------------------------------------------------------------------------
// K1: y[n, c] = sum_f x[n, f] * W[f, c]   (all fp32)
// ---------------------------------------------------------------------------
__global__ __launch_bounds__(256) void gemm_xw(const float* __restrict__ x,
                                               const float* __restrict__ W,
                                               float* __restrict__ y) {
    __shared__ float Ws[F * C];  // 8 KB
    for (int i = threadIdx.x; i < F * C; i += 256) Ws[i] = W[i];
    __syncthreads();

    const int node = blockIdx.x * 256 + threadIdx.x;
    if (node >= N_NODES) return;

    const float4* xp = (const float4*)(x + (size_t)node * F);
    float acc[C];
#pragma unroll
    for (int c = 0; c < C; c++) acc[c] = 0.f;

#pragma unroll
    for (int i = 0; i < 16; i++) {
        float4 v = xp[i];
        const int f = i * 4;
#pragma unroll
        for (int c = 0; c < C; c++) {
            acc[c] += v.x * Ws[(f + 0) * C + c];
            acc[c] += v.y * Ws[(f + 1) * C + c];
            acc[c] += v.z * Ws[(f + 2) * C + c];
            acc[c] += v.w * Ws[(f + 3) * C + c];
        }
    }

    float4* yo = (float4*)(y + (size_t)node * C);
#pragma unroll
    for (int i = 0; i < 8; i++)
        yo[i] = make_float4(acc[4 * i], acc[4 * i + 1], acc[4 * i + 2], acc[4 * i + 3]);
}

// ---------------------------------------------------------------------------
// K2: bucket histogram (LDS-aggregated)
// ---------------------------------------------------------------------------
__global__ __launch_bounds__(256) void hist_bkt(const int* __restrict__ rows,
                                                int* __restrict__ bktcnt) {
    __shared__ int h[NB];
    for (int i = threadIdx.x; i < NB; i += 256) h[i] = 0;
    __syncthreads();

    const int base = blockIdx.x * CHUNK;
#pragma unroll 4
    for (int j = 0; j < CHUNK / 256; j++) {
        const int e = base + j * 256 + threadIdx.x;
        if (e < NE_TOT) atomicAdd(&h[rows[e] >> BKT_SHIFT], 1);
    }
    __syncthreads();
    for (int i = threadIdx.x; i < NB; i += 256)
        if (h[i]) atomicAdd(&bktcnt[i], h[i]);
}

// ---------------------------------------------------------------------------
// K3: exclusive scan of bucket counts (single block) -> bkt_start, cursor
// ---------------------------------------------------------------------------
__global__ __launch_bounds__(1024) void scan_bkt(const int* __restrict__ cnt,
                                                 int* __restrict__ bkt_start,
                                                 int* __restrict__ cursor) {
    __shared__ int s[1024];
    const int t = threadIdx.x;
    s[t] = (t < NB) ? cnt[t] : 0;
    __syncthreads();
    for (int off = 1; off < 1024; off <<= 1) {
        int v = s[t];
        int a = (t >= off) ? s[t - off] : 0;
        __syncthreads();
        s[t] = v + a;
        __syncthreads();
    }
    if (t < NB) {
        const int ex = (t == 0) ? 0 : s[t - 1];
        bkt_start[t] = ex;
        cursor[t] = ex;
    }
    if (t == NB) bkt_start[NB] = s[NB - 1];
}

// ---------------------------------------------------------------------------
// K4: bin edges into buckets; record = (rowLocal<<20 | col, w_bits)
// ---------------------------------------------------------------------------
__global__ __launch_bounds__(256) void bin_k(
    const float* __restrict__ vals, const int* __restrict__ rows,
    const int* __restrict__ cols, const float* __restrict__ alpha,
    int* __restrict__ g_cursor, int2* __restrict__ recs) {
    __shared__ int h[NB];
    __shared__ int cur[NB];
    for (int i = threadIdx.x; i < NB; i += 256) h[i] = 0;
    __syncthreads();

    const int base = blockIdx.x * CHUNK;
#pragma unroll 4
    for (int j = 0; j < CHUNK / 256; j++) {
        const int e = base + j * 256 + threadIdx.x;
        if (e < NE_TOT) atomicAdd(&h[rows[e] >> BKT_SHIFT], 1);
    }
    __syncthreads();
    for (int i = threadIdx.x; i < NB; i += 256)
        cur[i] = atomicAdd(&g_cursor[i], h[i]);
    __syncthreads();
#pragma unroll 4
    for (int j = 0; j < CHUNK / 256; j++) {
        const int e = base + j * 256 + threadIdx.x;
        if (e >= NE_TOT) continue;
        const int row = rows[e];
        const int b = row >> BKT_SHIFT;
        const int k = (e >= 2 * E) ? 2 : (e >= E) ? 1 : 0;
        const float w = vals[e] * alpha[k];
        const int slot = atomicAdd(&cur[b], 1);
        const int packed = cols[e] | ((row & (ROWS_PER_BKT - 1)) << 20);
        recs[slot] = make_int2(packed, __float_as_int(w));
    }
}

// ---------------------------------------------------------------------------
// K5: accumulate — SPLIT blocks per bucket, 128x32 fp32 tile in LDS.
// 8 groups of 32 lanes; each group owns a CONTIGUOUS record run (sequential
// 64 B rec reads), unroll-8 for MLP. Native atomicAdd on LDS. Sub-blocks
// merge into out via global fp32 atomics; bias pre-seeded by sub-block 0.
// ---------------------------------------------------------------------------
__global__ __launch_bounds__(256) void acc_k(
    const int* __restrict__ bkt_start, const int2* __restrict__ recs,
    const float* __restrict__ y, const float* __restrict__ bias,
    float* __restrict__ out) {
    __shared__ float accs[ROWS_PER_BKT * C];  // 16 KB
    const int tid = threadIdx.x;
    const int b = blockIdx.x / SPLIT;
    const int s = blockIdx.x % SPLIT;

    // seed: sub-block 0 carries the bias so no finalize pass is needed
    if (s == 0) {
        for (int i = tid; i < ROWS_PER_BKT * C; i += 256) accs[i] = bias[i & (C - 1)];
    } else {
        for (int i = tid; i < ROWS_PER_BKT * C; i += 256) accs[i] = 0.f;
    }
    __syncthreads();

    const int start = bkt_start[b];
    const int len = bkt_start[b + 1] - start;
    const int bs = start + (int)(((long long)len * s) / SPLIT);
    const int be = start + (int)(((long long)len * (s + 1)) / SPLIT);

    const int grp = tid >> 5;   // 8 groups
    const int c = tid & 31;
    const int glen = be - bs;
    int i = bs + (glen * grp) / 8;
    const int gend = bs + (glen * (grp + 1)) / 8;

    for (; i + 8 <= gend; i += 8) {
        int2 r[8];
#pragma unroll
        for (int u = 0; u < 8; u++) r[u] = recs[i + u];
        float p[8];
#pragma unroll
        for (int u = 0; u < 8; u++) p[u] = y[(size_t)(r[u].x & COL_MASK) * C + c];
#pragma unroll
        for (int u = 0; u < 8; u++)
            atomicAdd(&accs[(r[u].x >> 20) * C + c], __int_as_float(r[u].y) * p[u]);
    }
    for (; i < gend; i++) {
        const int2 r0 = recs[i];
        const float p0 = y[(size_t)(r0.x & COL_MASK) * C + c];
        atomicAdd(&accs[(r0.x >> 20) * C + c], __int_as_float(r0.y) * p0);
    }
    __syncthreads();

    // flush tile into out (out pre-zeroed; merge across SPLIT sub-blocks)
    const int row0 = b << BKT_SHIFT;
    const int nrows = min(ROWS_PER_BKT, N_NODES - row0);
    for (int idx = tid; idx < nrows * C; idx += 256)
        unsafeAtomicAdd(&out[(size_t)row0 * C + idx], accs[idx]);
}

// ---------------------------------------------------------------------------
extern "C" void kernel_launch(void* const* d_in, const int* in_sizes, int n_in,
                              void* d_out, int out_size, void* d_ws, size_t ws_size,
                              hipStream_t stream) {
    const float* x         = (const float*)d_in[0];
    const float* edge_vals = (const float*)d_in[1];
    const float* W         = (const float*)d_in[2];
    const float* b         = (const float*)d_in[3];
    const float* alpha     = (const float*)d_in[4];
    const int*   edge_rows = (const int*)d_in[5];
    const int*   edge_cols = (const int*)d_in[6];
    float*       out       = (float*)d_out;          // [N, C] fp32

    // ws layout (4 B units) — 51.3 MB total, proven in R3/R4
    int* wsi = (int*)d_ws;
    float* y         = (float*)wsi;                  // 3,200,000 f32 (12.8 MB)
    int*   bktcnt    = wsi + 3200000;                // NB (pad 1024)
    int*   bkt_start = wsi + 3201024;                // NB+1 (pad 1024)
    int*   g_cursor  = wsi + 3202048;                // NB (pad 1024)
    int2*  recs      = (int2*)(wsi + 3203072);       // 4.8M int2 (38.4 MB)

    hipMemsetAsync(bktcnt, 0, NB * sizeof(int), stream);
    hipMemsetAsync(out, 0, (size_t)N_NODES * C * sizeof(float), stream);

    gemm_xw<<<(N_NODES + 255) / 256, 256, 0, stream>>>(x, W, y);

    hist_bkt<<<NBIN_BLK, 256, 0, stream>>>(edge_rows, bktcnt);
    scan_bkt<<<1, 1024, 0, stream>>>(bktcnt, bkt_start, g_cursor);
    bin_k<<<NBIN_BLK, 256, 0, stream>>>(edge_vals, edge_rows, edge_cols, alpha,
                                        g_cursor, recs);
    acc_k<<<NB * SPLIT, 256, 0, stream>>>(bkt_start, recs, y, b, out);
}

// Round 6
// 1072.430 us; speedup vs baseline: 1.1893x; 1.0207x over previous
//
#include <hip/hip_runtime.h>

#define N_NODES 100000
#define F 64
#define C 32
#define KH 3
#define E 1600000
#define NE_TOT (KH * E)                 // 4,800,000

#define BKT_SHIFT 7                     // 128 rows per bucket
#define ROWS_PER_BKT 128
#define NB ((N_NODES + ROWS_PER_BKT - 1) / ROWS_PER_BKT)   // 782
#define CHUNK 8192
#define NBIN_BLK ((NE_TOT + CHUNK - 1) / CHUNK)            // 586
#define COL_MASK 0xFFFFF
#define SPLIT 8                         // edge sub-ranges per bucket
#define U 8                             // unroll / prefetch batch

typedef unsigned short ushort;
typedef unsigned int uint;

__device__ __forceinline__ float bf2f(ushort u) {
    union { uint i; float f; } v; v.i = ((uint)u) << 16; return v.f;
}
__device__ __forceinline__ ushort f2bf(float f) {
    union { uint i; float f; } v; v.f = f;
    uint u = v.i;
    u += 0x7fffu + ((u >> 16) & 1u);   // RNE
    return (ushort)(u >> 16);
}

// ---------------------------------------------------------------------------
// K1: y[n, c] = sum_f x[n, f] * W[f, c]  (fp32 math, y stored bf16)
// ---------------------------------------------------------------------------
__global__ __launch_bounds__(256) void gemm_xw(const float* __restrict__ x,
                                               const float* __restrict__ W,
                                               ushort* __restrict__ y_h) {
    __shared__ float Ws[F * C];  // 8 KB
    for (int i = threadIdx.x; i < F * C; i += 256) Ws[i] = W[i];
    __syncthreads();

    const int node = blockIdx.x * 256 + threadIdx.x;
    if (node >= N_NODES) return;

    const float4* xp = (const float4*)(x + (size_t)node * F);
    float acc[C];
#pragma unroll
    for (int c = 0; c < C; c++) acc[c] = 0.f;

#pragma unroll
    for (int i = 0; i < 16; i++) {
        float4 v = xp[i];
        const int f = i * 4;
#pragma unroll
        for (int c = 0; c < C; c++) {
            acc[c] += v.x * Ws[(f + 0) * C + c];
            acc[c] += v.y * Ws[(f + 1) * C + c];
            acc[c] += v.z * Ws[(f + 2) * C + c];
            acc[c] += v.w * Ws[(f + 3) * C + c];
        }
    }

    uint pack[16];
#pragma unroll
    for (int i = 0; i < 16; i++)
        pack[i] = (uint)f2bf(acc[2 * i]) | ((uint)f2bf(acc[2 * i + 1]) << 16);
    uint4* yo = (uint4*)(y_h + (size_t)node * C);
#pragma unroll
    for (int i = 0; i < 4; i++)
        yo[i] = make_uint4(pack[4 * i], pack[4 * i + 1], pack[4 * i + 2], pack[4 * i + 3]);
}

// ---------------------------------------------------------------------------
// K2: bucket histogram (LDS-aggregated)
// ---------------------------------------------------------------------------
__global__ __launch_bounds__(256) void hist_bkt(const int* __restrict__ rows,
                                                int* __restrict__ bktcnt) {
    __shared__ int h[NB];
    for (int i = threadIdx.x; i < NB; i += 256) h[i] = 0;
    __syncthreads();

    const int base = blockIdx.x * CHUNK;
#pragma unroll 4
    for (int j = 0; j < CHUNK / 256; j++) {
        const int e = base + j * 256 + threadIdx.x;
        if (e < NE_TOT) atomicAdd(&h[rows[e] >> BKT_SHIFT], 1);
    }
    __syncthreads();
    for (int i = threadIdx.x; i < NB; i += 256)
        if (h[i]) atomicAdd(&bktcnt[i], h[i]);
}

// ---------------------------------------------------------------------------
// K3: exclusive scan of bucket counts (single block)
// ---------------------------------------------------------------------------
__global__ __launch_bounds__(1024) void scan_bkt(const int* __restrict__ cnt,
                                                 int* __restrict__ bkt_start,
                                                 int* __restrict__ cursor) {
    __shared__ int s[1024];
    const int t = threadIdx.x;
    s[t] = (t < NB) ? cnt[t] : 0;
    __syncthreads();
    for (int off = 1; off < 1024; off <<= 1) {
        int v = s[t];
        int a = (t >= off) ? s[t - off] : 0;
        __syncthreads();
        s[t] = v + a;
        __syncthreads();
    }
    if (t < NB) {
        const int ex = (t == 0) ? 0 : s[t - 1];
        bkt_start[t] = ex;
        cursor[t] = ex;
    }
    if (t == NB) bkt_start[NB] = s[NB - 1];
}

// ---------------------------------------------------------------------------
// K4: bin edges into buckets; record = (rowLocal<<20 | col, w_bits)
// ---------------------------------------------------------------------------
__global__ __launch_bounds__(256) void bin_k(
    const float* __restrict__ vals, const int* __restrict__ rows,
    const int* __restrict__ cols, const float* __restrict__ alpha,
    int* __restrict__ g_cursor, int2* __restrict__ recs) {
    __shared__ int h[NB];
    __shared__ int cur[NB];
    for (int i = threadIdx.x; i < NB; i += 256) h[i] = 0;
    __syncthreads();

    const int base = blockIdx.x * CHUNK;
#pragma unroll 4
    for (int j = 0; j < CHUNK / 256; j++) {
        const int e = base + j * 256 + threadIdx.x;
        if (e < NE_TOT) atomicAdd(&h[rows[e] >> BKT_SHIFT], 1);
    }
    __syncthreads();
    for (int i = threadIdx.x; i < NB; i += 256)
        cur[i] = atomicAdd(&g_cursor[i], h[i]);
    __syncthreads();
#pragma unroll 4
    for (int j = 0; j < CHUNK / 256; j++) {
        const int e = base + j * 256 + threadIdx.x;
        if (e >= NE_TOT) continue;
        const int row = rows[e];
        const int b = row >> BKT_SHIFT;
        const int k = (e >= 2 * E) ? 2 : (e >= E) ? 1 : 0;
        const float w = vals[e] * alpha[k];
        const int slot = atomicAdd(&cur[b], 1);
        const int packed = cols[e] | ((row & (ROWS_PER_BKT - 1)) << 20);
        recs[slot] = make_int2(packed, __float_as_int(w));
    }
}

// ---------------------------------------------------------------------------
// K5 v3: software-pipelined accumulate. SPLIT blocks/bucket, 8 groups of 32
// lanes, batch-U record loads with next-batch prefetch; bf16 y gather.
// ---------------------------------------------------------------------------
__global__ __launch_bounds__(256) void acc_k(
    const int* __restrict__ bkt_start, const int2* __restrict__ recs,
    const ushort* __restrict__ y_h, const float* __restrict__ bias,
    float* __restrict__ out) {
    __shared__ float accs[ROWS_PER_BKT * C];  // 16 KB
    const int tid = threadIdx.x;
    const int b = blockIdx.x / SPLIT;
    const int s = blockIdx.x % SPLIT;

    if (s == 0) {
        for (int i = tid; i < ROWS_PER_BKT * C; i += 256) accs[i] = bias[i & (C - 1)];
    } else {
        for (int i = tid; i < ROWS_PER_BKT * C; i += 256) accs[i] = 0.f;
    }
    __syncthreads();

    const int start = bkt_start[b];
    const int len = bkt_start[b + 1] - start;
    const int bs = start + (int)(((long long)len * s) / SPLIT);
    const int be = start + (int)(((long long)len * (s + 1)) / SPLIT);

    const int grp = tid >> 5;   // 8 groups
    const int c = tid & 31;
    const int glen = be - bs;
    int i = bs + (glen * grp) / 8;
    const int ge = bs + (glen * (grp + 1)) / 8;

    if (i + U <= ge) {
        int2 r[U];
#pragma unroll
        for (int u = 0; u < U; u++) r[u] = recs[i + u];

        while (i + 2 * U <= ge) {
            float p[U];
#pragma unroll
            for (int u = 0; u < U; u++)
                p[u] = bf2f(y_h[((size_t)(r[u].x & COL_MASK) << 5) + c]);
            int2 rn[U];
#pragma unroll
            for (int u = 0; u < U; u++) rn[u] = recs[i + U + u];
#pragma unroll
            for (int u = 0; u < U; u++)
                atomicAdd(&accs[(r[u].x >> 20) * C + c], __int_as_float(r[u].y) * p[u]);
#pragma unroll
            for (int u = 0; u < U; u++) r[u] = rn[u];
            i += U;
        }
        // final full batch already in registers
        {
            float p[U];
#pragma unroll
            for (int u = 0; u < U; u++)
                p[u] = bf2f(y_h[((size_t)(r[u].x & COL_MASK) << 5) + c]);
#pragma unroll
            for (int u = 0; u < U; u++)
                atomicAdd(&accs[(r[u].x >> 20) * C + c], __int_as_float(r[u].y) * p[u]);
            i += U;
        }
    }
    for (; i < ge; i++) {
        const int2 r0 = recs[i];
        const float p0 = bf2f(y_h[((size_t)(r0.x & COL_MASK) << 5) + c]);
        atomicAdd(&accs[(r0.x >> 20) * C + c], __int_as_float(r0.y) * p0);
    }
    __syncthreads();

    const int row0 = b << BKT_SHIFT;
    const int nrows = min(ROWS_PER_BKT, N_NODES - row0);
    for (int idx = tid; idx < nrows * C; idx += 256)
        unsafeAtomicAdd(&out[(size_t)row0 * C + idx], accs[idx]);
}

// ---------------------------------------------------------------------------
extern "C" void kernel_launch(void* const* d_in, const int* in_sizes, int n_in,
                              void* d_out, int out_size, void* d_ws, size_t ws_size,
                              hipStream_t stream) {
    const float* x         = (const float*)d_in[0];
    const float* edge_vals = (const float*)d_in[1];
    const float* W         = (const float*)d_in[2];
    const float* b         = (const float*)d_in[3];
    const float* alpha     = (const float*)d_in[4];
    const int*   edge_rows = (const int*)d_in[5];
    const int*   edge_cols = (const int*)d_in[6];
    float*       out       = (float*)d_out;          // [N, C] fp32

    // ws layout (4 B units) — ~44.9 MB total (52.4 MB proven safe)
    int* wsi = (int*)d_ws;
    ushort* y_h      = (ushort*)wsi;                 // 3.2M bf16 (6.4 MB) = 1.6M ints
    int*   bktcnt    = wsi + 1600000;                // NB (pad 1024)
    int*   bkt_start = wsi + 1601024;                // NB+1 (pad 1024)
    int*   g_cursor  = wsi + 1602048;                // NB (pad 1024)
    int2*  recs      = (int2*)(wsi + 1603072);       // 4.8M int2 (38.4 MB)

    hipMemsetAsync(bktcnt, 0, NB * sizeof(int), stream);
    hipMemsetAsync(out, 0, (size_t)N_NODES * C * sizeof(float), stream);

    gemm_xw<<<(N_NODES + 255) / 256, 256, 0, stream>>>(x, W, y_h);

    hist_bkt<<<NBIN_BLK, 256, 0, stream>>>(edge_rows, bktcnt);
    scan_bkt<<<1, 1024, 0, stream>>>(bktcnt, bkt_start, g_cursor);
    bin_k<<<NBIN_BLK, 256, 0, stream>>>(edge_vals, edge_rows, edge_cols, alpha,
                                        g_cursor, recs);
    acc_k<<<NB * SPLIT, 256, 0, stream>>>(bkt_start, recs, y_h, b, out);
}